// Round 11
// baseline (354.666 us; speedup 1.0000x reference)
//
#include <hip/hip_runtime.h>
#include <hip/hip_bf16.h>

typedef _Float16 f16x8 __attribute__((ext_vector_type(8)));
typedef _Float16 f16x4 __attribute__((ext_vector_type(4)));
typedef float f32x4 __attribute__((ext_vector_type(4)));

typedef __attribute__((address_space(1))) void GV;
typedef __attribute__((address_space(3))) void LV;

__device__ inline void async16(void* lds, const void* g) {
    __builtin_amdgcn_global_load_lds((GV*)g, (LV*)lds, 16, 0, 0);
}

// ---------------- fused cast f32 -> f16 for all 7 inputs ----------------
__global__ __launch_bounds__(256) void cast_all(
    const float* __restrict__ q, const float* __restrict__ k, const float* __restrict__ v,
    const float* __restrict__ wq, const float* __restrict__ wk,
    const float* __restrict__ wv, const float* __restrict__ wo, _Float16* __restrict__ ws)
{
    const long M1 = 1048576;
    const long tot = 6291456;  // total float4s
    for (long idx = (long)blockIdx.x * 256 + threadIdx.x; idx < tot;
         idx += (long)gridDim.x * 256) {
        const float* src; long local; long doff;
        if (idx < 1572864) {                    // q,k,v: 512K f4 each
            int seg = (int)(idx >> 19);
            src = seg == 0 ? q : (seg == 1 ? k : v);
            local = idx & 524287; doff = (long)seg * 2 * M1;
        } else if (idx < 5767168) {             // wq, wk: 2M f4 each
            int seg = (int)((idx - 1572864) >> 21);
            src = seg == 0 ? wq : wk;
            local = (idx - 1572864) & 2097151; doff = (6 + 8 * (long)seg) * M1;
        } else {                                 // wv, wo: 256K f4 each
            int seg = (int)((idx - 5767168) >> 18);
            src = seg == 0 ? wv : wo;
            local = (idx - 5767168) & 262143; doff = (22 + (long)seg) * M1;
        }
        float4 val = ((const float4*)src)[local];
        f16x4 o;
        o[0] = (_Float16)val.x; o[1] = (_Float16)val.y;
        o[2] = (_Float16)val.z; o[3] = (_Float16)val.w;
        *(f16x4*)&ws[doff + 4 * local] = o;
    }
}

// ---------------- V transpose: in [b][s][e] -> out [b][e][s] ----------------
__global__ __launch_bounds__(256) void transpose_v(const _Float16* __restrict__ in,
                                                   _Float16* __restrict__ out) {
    __shared__ _Float16 tile[64][66];
    int b = blockIdx.z;
    long base = (long)b * 1048576;
    int s0 = blockIdx.x * 64, e0 = blockIdx.y * 64;
    int tc = threadIdx.x & 63, tr = threadIdx.x >> 6;
    #pragma unroll
    for (int rr = 0; rr < 64; rr += 4)
        tile[tr + rr][tc] = in[base + (long)(s0 + tr + rr) * 1024 + e0 + tc];
    __syncthreads();
    #pragma unroll
    for (int rr = 0; rr < 64; rr += 4)
        out[base + (long)(e0 + tr + rr) * 1024 + s0 + tc] = tile[tc][tr + rr];
}

// ---------------- batched GEMM v2: C = A @ B^T, double-buffered staging ----------------
// RB = row-fragments per wave (tile M = RB*32). XS: flat-grid XCD-chunk swizzle.
// OMODE: 0 = f16 row-major, 1 = f32 row-major.
// {__syncthreads (drain stage(t)) -> issue stage(t+1) -> compute(t)}.
template<int RB, int XS, int OMODE>
__global__ __launch_bounds__(256) void gemm_bt(
    const _Float16* __restrict__ A0, const _Float16* __restrict__ B0, void* __restrict__ C0,
    int K, int lda, int ldb, int ldc,
    int az_div, long sa_hi, long sa_lo, long sb,
    int cz_div, long sc_hi, long sc_lo)
{
    __shared__ _Float16 As[2][RB * 32 * 64];
    __shared__ _Float16 Bs[2][128 * 64];
    int bx, by, bz;
    if (XS) {
        int p = blockIdx.x;
        int xcd = p & 7, s = p >> 3;
        int c, within;
        if (s < 256) { c = xcd + 8 * (s >> 6); within = s & 63; }
        else         { c = 32 + (xcd >> 2); within = (xcd & 3) * 16 + (s - 256); }
        bz = c >> 1;
        by = (c & 1) * 8 + (within >> 3);
        bx = within & 7;
    } else { bx = blockIdx.x; by = blockIdx.y; bz = blockIdx.z; }
    int z = bz;
    const _Float16* A = A0 + (long)(z / az_div) * sa_hi + (long)(z % az_div) * sa_lo;
    const _Float16* B = B0 + (long)z * sb;
    long coff = (long)(z / cz_div) * sc_hi + (long)(z % cz_div) * sc_lo;
    int rowbase = by * (RB * 32), colbase = bx * 128;
    int t = threadIdx.x, wave = t >> 6, lane = t & 63;
    int l15 = lane & 15, lg = lane >> 4;
    int srow = t >> 3, scol = (t & 7) * 8;
    int wm = wave >> 1, wn = wave & 1;
    f32x4 acc[RB][4] = {};
    const int nt = K >> 6;

    // prologue: stage k-step 0 into buf 0
    #pragma unroll
    for (int ii = 0; ii < RB; ii++) {
        int r = srow + ii * 32;
        async16(&As[0][r * 64 + scol], A + (long)(rowbase + r) * lda + scol);
    }
    #pragma unroll
    for (int ii = 0; ii < 4; ii++) {
        int r = srow + ii * 32;
        async16(&Bs[0][r * 64 + scol], B + (long)(colbase + r) * ldb + scol);
    }

    for (int ts = 0; ts < nt; ts++) {
        __syncthreads();   // drain stage(ts); all reads of buf[(ts+1)&1] finished
        if (ts + 1 < nt) {
            int k1 = (ts + 1) << 6;
            int p1 = (ts + 1) & 1;
            #pragma unroll
            for (int ii = 0; ii < RB; ii++) {
                int r = srow + ii * 32;
                async16(&As[p1][r * 64 + scol], A + (long)(rowbase + r) * lda + k1 + scol);
            }
            #pragma unroll
            for (int ii = 0; ii < 4; ii++) {
                int r = srow + ii * 32;
                async16(&Bs[p1][r * 64 + scol], B + (long)(colbase + r) * ldb + k1 + scol);
            }
        }
        int pc = ts & 1;
        #pragma unroll
        for (int ks = 0; ks < 2; ks++) {
            f16x8 af[RB], bfr[4];
            #pragma unroll
            for (int m = 0; m < RB; m++)
                af[m] = *(const f16x8*)&As[pc][(wm * (RB * 16) + m * 16 + l15) * 64 + ks * 32 + lg * 8];
            #pragma unroll
            for (int n = 0; n < 4; n++)
                bfr[n] = *(const f16x8*)&Bs[pc][(wn * 64 + n * 16 + l15) * 64 + ks * 32 + lg * 8];
            #pragma unroll
            for (int m = 0; m < RB; m++)
                #pragma unroll
                for (int n = 0; n < 4; n++)
                    acc[m][n] = __builtin_amdgcn_mfma_f32_16x16x32_f16(af[m], bfr[n], acc[m][n], 0, 0, 0);
        }
    }
    #pragma unroll
    for (int m = 0; m < RB; m++) {
        int row = rowbase + wm * (RB * 16) + m * 16 + lg * 4;
        #pragma unroll
        for (int n = 0; n < 4; n++) {
            int col = colbase + wn * 64 + n * 16 + l15;
            #pragma unroll
            for (int r = 0; r < 4; r++) {
                long idx = coff + (long)(row + r) * ldc + col;
                if (OMODE == 1) ((float*)C0)[idx] = acc[m][n][r];
                else ((_Float16*)C0)[idx] = (_Float16)acc[m][n][r];
            }
        }
    }
}

// ---------------- fused attn v10: v8 sync, t-tile 32, 16 waves ----------------
// 512 blocks (XCD-swizzled: XCD k owns bh {2k,2k+1}), 1024 threads = 16 waves.
// Block = 32 t-rows x 1024 s of one (b,h): K staged once serves BOTH t-halves
// -> aggregate K DMA halves (2GB -> 1GB) and block-rounds 2 -> 1.
// Wave w: tw = w>>3 (t-half), iw = w&7 with cw = iw>>2 (64-row half of the
// staged 128-row chunk), sw = iw&3 (16-col subtile) — v8's mapping per t-half.
// 64 linearized chunk-steps m=i*8+c; buffers alternate on c&1.
// {barrier(drain m) -> issue stage(m+1, buf^1) -> compute m}  (v8-proven).
__global__ __launch_bounds__(1024, 2) void attn_fused(
    const _Float16* __restrict__ Qbuf, const _Float16* __restrict__ Kbuf,
    float* __restrict__ attn_out, _Float16* __restrict__ Pbar)
{
    __shared__ _Float16 Kc[2][128 * 128];  // 2 x 32 KB
    __shared__ float red[2][8][16];
    int id = blockIdx.x;
    int orig = (id & 7) * 64 + (id >> 3);   // XCD k owns bh {2k,2k+1}
    int t0 = (orig & 31) * 32;
    int bh = orig >> 5, h = bh & 7, b = bh >> 3;
    int tid = threadIdx.x, wave = tid >> 6, lane = tid & 63;
    int l15 = lane & 15, lg = lane >> 4;
    int tw = wave >> 3, iw = wave & 7;
    int cw = iw >> 2, sw = iw & 3;
    int brow = cw * 64 + sw * 16 + l15;      // s-col row within staged chunk
    const float scale = 0.088388347648318447f;  // 1/sqrt(128)
    float acc[8][4] = {};

    // hoisted per-thread bases: staging covers rows srow and srow+64
    int srow = tid >> 4;                      // 0..63
    int scolB = (tid & 15) << 4;              // byte col 0..240
    int gcolB = scolB ^ ((srow & 7) << 4);    // inverse swizzle on global source
    int ldsoff = srow * 256 + scolB;
    const char* pk = (const char*)(Kbuf + (long)b * 1048576 + h * 128)
                     + (long)srow * 2048 + gcolB;
    const char* pq = (const char*)(Qbuf + ((long)(b * 1024 + t0 + tw * 16 + l15)) * 1024 + h * 128)
                     + lg * 16;
    int swz = (brow & 7) << 4;
    int rdoff[4];
    #pragma unroll
    for (int kk = 0; kk < 4; kk++)
        rdoff[kk] = brow * 256 + ((kk * 64 + lg * 16) ^ swz);

    // prologue: stage step 0 into buf 0 (rows srow, srow+64)
    {
        char* lb = (char*)Kc[0] + ldsoff;
        async16(lb, pk);
        async16(lb + 16384, pk + 131072);
    }

    #pragma unroll 1
    for (int i = 0; i < 8; i++) {
        f16x8 aq[4];
        #pragma unroll
        for (int kk = 0; kk < 4; kk++)
            aq[kk] = *(const f16x8*)(pq + kk * 64);
        pq += 4194304;   // next i (+2M f16)
        float s[8][4];
        float rs[4] = {0.f, 0.f, 0.f, 0.f};
        #pragma unroll
        for (int c = 0; c < 8; c++) {
            int m = i * 8 + c;
            __syncthreads();   // drain stage(m); all reads of buf[(m+1)&1] done
            pk += 262144;                   // chunk + 1 (128 rows x 2048 B)
            if (c == 7) pk += 2097152;      // head boundary: total +4MB per i
            if (m < 63) {
                char* lb = (char*)Kc[(c + 1) & 1] + ldsoff;
                async16(lb, pk);
                async16(lb + 16384, pk + 131072);
            }
            const char* kc = (const char*)Kc[c & 1];
            f32x4 sv = {0.f, 0.f, 0.f, 0.f};
            #pragma unroll
            for (int kk = 0; kk < 4; kk++) {
                f16x8 bk = *(const f16x8*)(kc + rdoff[kk]);
                sv = __builtin_amdgcn_mfma_f32_16x16x32_f16(aq[kk], bk, sv, 0, 0, 0);
            }
            #pragma unroll
            for (int r = 0; r < 4; r++) {
                float e = __expf(sv[r] * scale);
                s[c][r] = e;
                rs[r] += e;
            }
        }
        // row-sum reduce: across l15 lanes, then across the 8 waves of this t-half
        #pragma unroll
        for (int off = 1; off < 16; off <<= 1)
            #pragma unroll
            for (int r = 0; r < 4; r++) rs[r] += __shfl_xor(rs[r], off, 64);
        if (l15 == 0) {
            #pragma unroll
            for (int r = 0; r < 4; r++) red[tw][iw][lg * 4 + r] = rs[r];
        }
        __syncthreads();
        #pragma unroll
        for (int r = 0; r < 4; r++) {
            int row = lg * 4 + r;
            float tot = red[tw][0][row] + red[tw][1][row] + red[tw][2][row] + red[tw][3][row]
                      + red[tw][4][row] + red[tw][5][row] + red[tw][6][row] + red[tw][7][row];
            float rinv = 0.125f / tot;
            #pragma unroll
            for (int c = 0; c < 8; c++) acc[c][r] += s[c][r] * rinv;
        }
        __syncthreads();   // red reads done before next i's writes
    }

    long rbase = ((long)(bh * 1024 + t0 + tw * 16)) * 1024;
    #pragma unroll
    for (int c = 0; c < 8; c++) {
        int scol = c * 128 + cw * 64 + sw * 16 + l15;
        #pragma unroll
        for (int r = 0; r < 4; r++) {
            long idx = rbase + (long)(lg * 4 + r) * 1024 + scol;
            attn_out[idx] = acc[c][r];
            Pbar[idx] = (_Float16)acc[c][r];
        }
    }
}

extern "C" void kernel_launch(void* const* d_in, const int* in_sizes, int n_in,
                              void* d_out, int out_size, void* d_ws, size_t ws_size,
                              hipStream_t stream) {
    const long M1 = 1048576;
    _Float16* ws = (_Float16*)d_ws;
    _Float16* q16  = ws;             // 2M elts (query; key at +2M, value at +4M)
    _Float16* wq16 = ws + 6 * M1;    // 8M (Wk at +8M, Wv at +16M)
    _Float16* wo16 = ws + 23 * M1;   // 1M
    _Float16* Qbuf = ws + 24 * M1;   // 16M row-major Q (Kbuf at +16M, Vbuf at +32M)
    _Float16* Vbuf = ws + 56 * M1;   // 2M  (== Qbuf + 32M)
    _Float16* Vt   = ws + 58 * M1;   // 2M
    _Float16* Pb   = ws + 60 * M1;   // 16M
    _Float16* Hbar = ws + 76 * M1;   // 2M
    float* out = (float*)d_out;
    float* attn_out = out + 2 * M1;

    // all 7 casts in one dispatch
    cast_all<<<2048, 256, 0, stream>>>(
        (const float*)d_in[0], (const float*)d_in[1], (const float*)d_in[2],
        (const float*)d_in[3], (const float*)d_in[4], (const float*)d_in[5],
        (const float*)d_in[6], ws);

    // Projections, one dispatch (XCD-chunk swizzled flat grid):
    // z=0..7 Q_i = query @ Wq[i]^T; z=8..15 K_i; z=16 V = value @ Wv^T.
    gemm_bt<4, 1, 0><<<2176, 256, 0, stream>>>(
        q16, wq16, Qbuf, 1024, 1024, 1024, 1024,
        /*az*/ 8, 2 * M1, 0, /*sb*/ M1,
        /*cz*/ 16, 32 * M1, 2 * M1);
    // V transpose -> Vt[b][e][s]
    transpose_v<<<dim3(16, 16, 2), 256, 0, stream>>>(Vbuf, Vt);
    // fused scores+softmax+mean_i -> attention (f32) + Pbar (f16)
    attn_fused<<<512, 1024, 0, stream>>>(Qbuf, Qbuf + 16 * M1, attn_out, Pb);
    // PV: head[b][t][h*128+n] = sum_s Pbar[(b,h)][t][s] * Vt[b][h*128+n][s]
    gemm_bt<2, 0, 0><<<dim3(1, 16, 16), 256, 0, stream>>>(
        Pb, Vt, Hbar, 1024, 1024, 1024, 1024,
        /*az*/ 16, 0, M1, /*sb*/ M1 / 8,
        /*cz*/ 8, M1, 128);
    // out = head_mean @ Wo^T  (f32 out)
    gemm_bt<2, 0, 1><<<dim3(8, 32, 1), 256, 0, stream>>>(
        Hbar, wo16, out, 1024, 1024, 1024, 1024,
        1, 0, 0, 0, 1, 0, 0);
}

// Round 12
// 353.779 us; speedup vs baseline: 1.0025x; 1.0025x over previous
//
#include <hip/hip_runtime.h>
#include <hip/hip_bf16.h>

typedef _Float16 f16x8 __attribute__((ext_vector_type(8)));
typedef _Float16 f16x4 __attribute__((ext_vector_type(4)));
typedef float f32x4 __attribute__((ext_vector_type(4)));

typedef __attribute__((address_space(1))) void GV;
typedef __attribute__((address_space(3))) void LV;

__device__ inline void async16(void* lds, const void* g) {
    __builtin_amdgcn_global_load_lds((GV*)g, (LV*)lds, 16, 0, 0);
}

// ---------------- fused cast f32 -> f16 for all 7 inputs ----------------
__global__ __launch_bounds__(256) void cast_all(
    const float* __restrict__ q, const float* __restrict__ k, const float* __restrict__ v,
    const float* __restrict__ wq, const float* __restrict__ wk,
    const float* __restrict__ wv, const float* __restrict__ wo, _Float16* __restrict__ ws)
{
    const long M1 = 1048576;
    const long tot = 6291456;  // total float4s
    for (long idx = (long)blockIdx.x * 256 + threadIdx.x; idx < tot;
         idx += (long)gridDim.x * 256) {
        const float* src; long local; long doff;
        if (idx < 1572864) {                    // q,k,v: 512K f4 each
            int seg = (int)(idx >> 19);
            src = seg == 0 ? q : (seg == 1 ? k : v);
            local = idx & 524287; doff = (long)seg * 2 * M1;
        } else if (idx < 5767168) {             // wq, wk: 2M f4 each
            int seg = (int)((idx - 1572864) >> 21);
            src = seg == 0 ? wq : wk;
            local = (idx - 1572864) & 2097151; doff = (6 + 8 * (long)seg) * M1;
        } else {                                 // wv, wo: 256K f4 each
            int seg = (int)((idx - 5767168) >> 18);
            src = seg == 0 ? wv : wo;
            local = (idx - 5767168) & 262143; doff = (22 + (long)seg) * M1;
        }
        float4 val = ((const float4*)src)[local];
        f16x4 o;
        o[0] = (_Float16)val.x; o[1] = (_Float16)val.y;
        o[2] = (_Float16)val.z; o[3] = (_Float16)val.w;
        *(f16x4*)&ws[doff + 4 * local] = o;
    }
}

// ---------------- V transpose: in [b][s][e] -> out [b][e][s] ----------------
__global__ __launch_bounds__(256) void transpose_v(const _Float16* __restrict__ in,
                                                   _Float16* __restrict__ out) {
    __shared__ _Float16 tile[64][66];
    int b = blockIdx.z;
    long base = (long)b * 1048576;
    int s0 = blockIdx.x * 64, e0 = blockIdx.y * 64;
    int tc = threadIdx.x & 63, tr = threadIdx.x >> 6;
    #pragma unroll
    for (int rr = 0; rr < 64; rr += 4)
        tile[tr + rr][tc] = in[base + (long)(s0 + tr + rr) * 1024 + e0 + tc];
    __syncthreads();
    #pragma unroll
    for (int rr = 0; rr < 64; rr += 4)
        out[base + (long)(e0 + tr + rr) * 1024 + s0 + tc] = tile[tc][tr + rr];
}

// ---------------- batched GEMM v2: C = A @ B^T, double-buffered staging ----------------
// RB = row-fragments per wave (tile M = RB*32). XS: flat-grid XCD-chunk swizzle.
// OMODE: 0 = f16 row-major, 1 = f32 row-major.
// {__syncthreads (drain stage(t)) -> issue stage(t+1) -> compute(t)}.
template<int RB, int XS, int OMODE>
__global__ __launch_bounds__(256) void gemm_bt(
    const _Float16* __restrict__ A0, const _Float16* __restrict__ B0, void* __restrict__ C0,
    int K, int lda, int ldb, int ldc,
    int az_div, long sa_hi, long sa_lo, long sb,
    int cz_div, long sc_hi, long sc_lo)
{
    __shared__ _Float16 As[2][RB * 32 * 64];
    __shared__ _Float16 Bs[2][128 * 64];
    int bx, by, bz;
    if (XS) {
        int p = blockIdx.x;
        int xcd = p & 7, s = p >> 3;
        int c, within;
        if (s < 256) { c = xcd + 8 * (s >> 6); within = s & 63; }
        else         { c = 32 + (xcd >> 2); within = (xcd & 3) * 16 + (s - 256); }
        bz = c >> 1;
        by = (c & 1) * 8 + (within >> 3);
        bx = within & 7;
    } else { bx = blockIdx.x; by = blockIdx.y; bz = blockIdx.z; }
    int z = bz;
    const _Float16* A = A0 + (long)(z / az_div) * sa_hi + (long)(z % az_div) * sa_lo;
    const _Float16* B = B0 + (long)z * sb;
    long coff = (long)(z / cz_div) * sc_hi + (long)(z % cz_div) * sc_lo;
    int rowbase = by * (RB * 32), colbase = bx * 128;
    int t = threadIdx.x, wave = t >> 6, lane = t & 63;
    int l15 = lane & 15, lg = lane >> 4;
    int srow = t >> 3, scol = (t & 7) * 8;
    int wm = wave >> 1, wn = wave & 1;
    f32x4 acc[RB][4] = {};
    const int nt = K >> 6;

    #pragma unroll
    for (int ii = 0; ii < RB; ii++) {
        int r = srow + ii * 32;
        async16(&As[0][r * 64 + scol], A + (long)(rowbase + r) * lda + scol);
    }
    #pragma unroll
    for (int ii = 0; ii < 4; ii++) {
        int r = srow + ii * 32;
        async16(&Bs[0][r * 64 + scol], B + (long)(colbase + r) * ldb + scol);
    }

    for (int ts = 0; ts < nt; ts++) {
        __syncthreads();
        if (ts + 1 < nt) {
            int k1 = (ts + 1) << 6;
            int p1 = (ts + 1) & 1;
            #pragma unroll
            for (int ii = 0; ii < RB; ii++) {
                int r = srow + ii * 32;
                async16(&As[p1][r * 64 + scol], A + (long)(rowbase + r) * lda + k1 + scol);
            }
            #pragma unroll
            for (int ii = 0; ii < 4; ii++) {
                int r = srow + ii * 32;
                async16(&Bs[p1][r * 64 + scol], B + (long)(colbase + r) * ldb + k1 + scol);
            }
        }
        int pc = ts & 1;
        #pragma unroll
        for (int ks = 0; ks < 2; ks++) {
            f16x8 af[RB], bfr[4];
            #pragma unroll
            for (int m = 0; m < RB; m++)
                af[m] = *(const f16x8*)&As[pc][(wm * (RB * 16) + m * 16 + l15) * 64 + ks * 32 + lg * 8];
            #pragma unroll
            for (int n = 0; n < 4; n++)
                bfr[n] = *(const f16x8*)&Bs[pc][(wn * 64 + n * 16 + l15) * 64 + ks * 32 + lg * 8];
            #pragma unroll
            for (int m = 0; m < RB; m++)
                #pragma unroll
                for (int n = 0; n < 4; n++)
                    acc[m][n] = __builtin_amdgcn_mfma_f32_16x16x32_f16(af[m], bfr[n], acc[m][n], 0, 0, 0);
        }
    }
    #pragma unroll
    for (int m = 0; m < RB; m++) {
        int row = rowbase + wm * (RB * 16) + m * 16 + lg * 4;
        #pragma unroll
        for (int n = 0; n < 4; n++) {
            int col = colbase + wn * 64 + n * 16 + l15;
            #pragma unroll
            for (int r = 0; r < 4; r++) {
                long idx = coff + (long)(row + r) * ldc + col;
                if (OMODE == 1) ((float*)C0)[idx] = acc[m][n][r];
                else ((_Float16*)C0)[idx] = (_Float16)acc[m][n][r];
            }
        }
    }
}

// ---------------- fused attn v11: v8 geometry + T4 counted-vmcnt depth-3 pipeline ----------------
// 1024 blocks (XCD-swizzled), 512 threads = 8 waves; block = 16 t-rows x 1024 s
// of one (b,h). 64 chunk-steps m=i*8+c; 4 LDS buffers (128 KB, 1 block/CU),
// stage(n) issued at step n-3 (wrap-around (m+3)&63 keeps the FIFO uniform).
// Step: {s_waitcnt vmcnt(8) lgkmcnt(0) -> s_barrier -> issue stage((m+3)&63)
//        -> ds_read+MFMA+exp}. vmcnt(8) = stages m+1,m+2 allowed in flight;
// FIFO retire => stage(m) landed. Reduction barriers are lgkm-only so the
// vmem pipeline survives head boundaries.
__global__ __launch_bounds__(512, 2) void attn_fused(
    const _Float16* __restrict__ Qbuf, const _Float16* __restrict__ Kbuf,
    float* __restrict__ attn_out, _Float16* __restrict__ Pbar)
{
    __shared__ _Float16 Kc[4][128 * 128];  // 4 x 32 KB
    __shared__ float red[8][16];
    int id = blockIdx.x;
    int orig = (id & 7) * 128 + (id >> 3);   // XCD k owns bh {2k,2k+1}
    int t0 = (orig & 63) * 16;
    int bh = orig >> 6, h = bh & 7, b = bh >> 3;
    int tid = threadIdx.x, wave = tid >> 6, lane = tid & 63;
    int l15 = lane & 15, lg = lane >> 4;
    int cw = wave >> 2, sw = wave & 3;
    int brow = cw * 64 + sw * 16 + l15;
    const float scale = 0.088388347648318447f;  // 1/sqrt(128)
    float acc[8][4] = {};

    // hoisted per-thread bases
    int srow = tid >> 4;
    int scolB = (tid & 15) << 4;
    int gcolB = scolB ^ ((srow & 7) << 4);    // inverse swizzle on global source
    int ldsoff = srow * 256 + scolB;
    const char* pkb = (const char*)(Kbuf + (long)b * 1048576 + h * 128)
                      + (long)srow * 2048 + gcolB;
    const char* pq = (const char*)(Qbuf + ((long)(b * 1024 + t0 + l15)) * 1024 + h * 128)
                     + lg * 16;
    int swz = (brow & 7) << 4;
    int rdoff[4];
    #pragma unroll
    for (int kk = 0; kk < 4; kk++)
        rdoff[kk] = brow * 256 + ((kk * 64 + lg * 16) ^ swz);

    // prologue: stage steps 0,1,2 into bufs 0,1,2 (all within head 0)
    #pragma unroll
    for (int mp = 0; mp < 3; mp++) {
        char* lb = (char*)Kc[mp] + ldsoff;
        const char* ps = pkb + (long)mp * 262144;
        #pragma unroll
        for (int j = 0; j < 4; j++)
            async16(lb + j * 8192, ps + (long)j * 65536);
    }

    #pragma unroll 1
    for (int i = 0; i < 8; i++) {
        f16x8 aq[4];
        #pragma unroll
        for (int kk = 0; kk < 4; kk++)
            aq[kk] = *(const f16x8*)(pq + kk * 64);
        pq += 4194304;   // next i (+2M f16)
        float s[8][4];
        float rs[4] = {0.f, 0.f, 0.f, 0.f};
        #pragma unroll
        for (int c = 0; c < 8; c++) {
            int m = i * 8 + c;
            // counted-vmcnt barrier: stage(m) landed; reads of buf[(m+3)&3]
            // (done at step m-1) retired via lgkmcnt(0)
            asm volatile("s_waitcnt vmcnt(8) lgkmcnt(0)" ::: "memory");
            __builtin_amdgcn_s_barrier();
            {
                int n = (m + 3) & 63;   // wrap keeps FIFO depth uniform at tail
                char* lb = (char*)Kc[(c + 3) & 3] + ldsoff;   // (m+3)&3 == (c+3)&3
                const char* ps = pkb + (long)(n >> 3) * 4194304 + (long)(n & 7) * 262144;
                #pragma unroll
                for (int j = 0; j < 4; j++)
                    async16(lb + j * 8192, ps + (long)j * 65536);
            }
            const char* kc = (const char*)Kc[c & 3];          // m&3 == c&3
            f32x4 sv = {0.f, 0.f, 0.f, 0.f};
            #pragma unroll
            for (int kk = 0; kk < 4; kk++) {
                f16x8 bk = *(const f16x8*)(kc + rdoff[kk]);
                sv = __builtin_amdgcn_mfma_f32_16x16x32_f16(aq[kk], bk, sv, 0, 0, 0);
            }
            #pragma unroll
            for (int r = 0; r < 4; r++) {
                float e = __expf(sv[r] * scale);
                s[c][r] = e;
                rs[r] += e;
            }
        }
        // row-sum reduce: across l15 lanes, then across all 8 waves.
        // lgkm-only barriers: do NOT drain vmcnt (pipeline survives head boundary).
        #pragma unroll
        for (int off = 1; off < 16; off <<= 1)
            #pragma unroll
            for (int r = 0; r < 4; r++) rs[r] += __shfl_xor(rs[r], off, 64);
        if (l15 == 0) {
            #pragma unroll
            for (int r = 0; r < 4; r++) red[wave][lg * 4 + r] = rs[r];
        }
        asm volatile("s_waitcnt lgkmcnt(0)" ::: "memory");
        __builtin_amdgcn_s_barrier();
        #pragma unroll
        for (int r = 0; r < 4; r++) {
            int row = lg * 4 + r;
            float tot = red[0][row] + red[1][row] + red[2][row] + red[3][row]
                      + red[4][row] + red[5][row] + red[6][row] + red[7][row];
            float rinv = 0.125f / tot;
            #pragma unroll
            for (int c = 0; c < 8; c++) acc[c][r] += s[c][r] * rinv;
        }
        asm volatile("s_waitcnt lgkmcnt(0)" ::: "memory");
        __builtin_amdgcn_s_barrier();
    }

    long rbase = ((long)(bh * 1024 + t0)) * 1024;
    #pragma unroll
    for (int c = 0; c < 8; c++) {
        int scol = c * 128 + cw * 64 + sw * 16 + l15;
        #pragma unroll
        for (int r = 0; r < 4; r++) {
            long idx = rbase + (long)(lg * 4 + r) * 1024 + scol;
            attn_out[idx] = acc[c][r];
            Pbar[idx] = (_Float16)acc[c][r];
        }
    }
}

extern "C" void kernel_launch(void* const* d_in, const int* in_sizes, int n_in,
                              void* d_out, int out_size, void* d_ws, size_t ws_size,
                              hipStream_t stream) {
    const long M1 = 1048576;
    _Float16* ws = (_Float16*)d_ws;
    _Float16* q16  = ws;             // 2M elts (query; key at +2M, value at +4M)
    _Float16* wq16 = ws + 6 * M1;    // 8M (Wk at +8M, Wv at +16M)
    _Float16* wo16 = ws + 23 * M1;   // 1M
    _Float16* Qbuf = ws + 24 * M1;   // 16M row-major Q (Kbuf at +16M, Vbuf at +32M)
    _Float16* Vbuf = ws + 56 * M1;   // 2M  (== Qbuf + 32M)
    _Float16* Vt   = ws + 58 * M1;   // 2M
    _Float16* Pb   = ws + 60 * M1;   // 16M
    _Float16* Hbar = ws + 76 * M1;   // 2M
    float* out = (float*)d_out;
    float* attn_out = out + 2 * M1;

    // all 7 casts in one dispatch
    cast_all<<<2048, 256, 0, stream>>>(
        (const float*)d_in[0], (const float*)d_in[1], (const float*)d_in[2],
        (const float*)d_in[3], (const float*)d_in[4], (const float*)d_in[5],
        (const float*)d_in[6], ws);

    // Projections, one dispatch (XCD-chunk swizzled flat grid):
    // z=0..7 Q_i = query @ Wq[i]^T; z=8..15 K_i; z=16 V = value @ Wv^T.
    gemm_bt<4, 1, 0><<<2176, 256, 0, stream>>>(
        q16, wq16, Qbuf, 1024, 1024, 1024, 1024,
        /*az*/ 8, 2 * M1, 0, /*sb*/ M1,
        /*cz*/ 16, 32 * M1, 2 * M1);
    // V transpose -> Vt[b][e][s]
    transpose_v<<<dim3(16, 16, 2), 256, 0, stream>>>(Vbuf, Vt);
    // fused scores+softmax+mean_i -> attention (f32) + Pbar (f16)
    attn_fused<<<1024, 512, 0, stream>>>(Qbuf, Qbuf + 16 * M1, attn_out, Pb);
    // PV: head[b][t][h*128+n] = sum_s Pbar[(b,h)][t][s] * Vt[b][h*128+n][s]
    gemm_bt<2, 0, 0><<<dim3(1, 16, 16), 256, 0, stream>>>(
        Pb, Vt, Hbar, 1024, 1024, 1024, 1024,
        /*az*/ 16, 0, M1, /*sb*/ M1 / 8,
        /*cz*/ 8, M1, 128);
    // out = head_mean @ Wo^T  (f32 out)
    gemm_bt<2, 0, 1><<<dim3(8, 32, 1), 256, 0, stream>>>(
        Hbar, wo16, out, 1024, 1024, 1024, 1024,
        1, 0, 0, 0, 1, 0, 0);
}

// Round 13
// 304.251 us; speedup vs baseline: 1.1657x; 1.1628x over previous
//
#include <hip/hip_runtime.h>
#include <hip/hip_bf16.h>

typedef _Float16 f16x8 __attribute__((ext_vector_type(8)));
typedef _Float16 f16x4 __attribute__((ext_vector_type(4)));
typedef float f32x4 __attribute__((ext_vector_type(4)));

typedef __attribute__((address_space(1))) void GV;
typedef __attribute__((address_space(3))) void LV;

__device__ inline void async16(void* lds, const void* g) {
    __builtin_amdgcn_global_load_lds((GV*)g, (LV*)lds, 16, 0, 0);
}

// ---------------- fused cast f32 -> f16 for all 7 inputs ----------------
__global__ __launch_bounds__(256) void cast_all(
    const float* __restrict__ q, const float* __restrict__ k, const float* __restrict__ v,
    const float* __restrict__ wq, const float* __restrict__ wk,
    const float* __restrict__ wv, const float* __restrict__ wo, _Float16* __restrict__ ws)
{
    const long M1 = 1048576;
    const long tot = 6291456;  // total float4s
    for (long idx = (long)blockIdx.x * 256 + threadIdx.x; idx < tot;
         idx += (long)gridDim.x * 256) {
        const float* src; long local; long doff;
        if (idx < 1572864) {                    // q,k,v: 512K f4 each
            int seg = (int)(idx >> 19);
            src = seg == 0 ? q : (seg == 1 ? k : v);
            local = idx & 524287; doff = (long)seg * 2 * M1;
        } else if (idx < 5767168) {             // wq, wk: 2M f4 each
            int seg = (int)((idx - 1572864) >> 21);
            src = seg == 0 ? wq : wk;
            local = (idx - 1572864) & 2097151; doff = (6 + 8 * (long)seg) * M1;
        } else {                                 // wv, wo: 256K f4 each
            int seg = (int)((idx - 5767168) >> 18);
            src = seg == 0 ? wv : wo;
            local = (idx - 5767168) & 262143; doff = (22 + (long)seg) * M1;
        }
        float4 val = ((const float4*)src)[local];
        f16x4 o;
        o[0] = (_Float16)val.x; o[1] = (_Float16)val.y;
        o[2] = (_Float16)val.z; o[3] = (_Float16)val.w;
        *(f16x4*)&ws[doff + 4 * local] = o;
    }
}

// ---------------- V transpose: in [b][s][e] -> out [b][e][s] ----------------
__global__ __launch_bounds__(256) void transpose_v(const _Float16* __restrict__ in,
                                                   _Float16* __restrict__ out) {
    __shared__ _Float16 tile[64][66];
    int b = blockIdx.z;
    long base = (long)b * 1048576;
    int s0 = blockIdx.x * 64, e0 = blockIdx.y * 64;
    int tc = threadIdx.x & 63, tr = threadIdx.x >> 6;
    #pragma unroll
    for (int rr = 0; rr < 64; rr += 4)
        tile[tr + rr][tc] = in[base + (long)(s0 + tr + rr) * 1024 + e0 + tc];
    __syncthreads();
    #pragma unroll
    for (int rr = 0; rr < 64; rr += 4)
        out[base + (long)(e0 + tr + rr) * 1024 + s0 + tc] = tile[tc][tr + rr];
}

// ---------------- batched GEMM v2: C = A @ B^T, double-buffered staging ----------------
// RB = row-fragments per wave (tile M = RB*32). XS: flat-grid XCD-chunk swizzle.
// OMODE: 0 = f16 row-major, 1 = f32 row-major.
// {__syncthreads (drain stage(t)) -> issue stage(t+1) -> compute(t)}.
template<int RB, int XS, int OMODE>
__global__ __launch_bounds__(256) void gemm_bt(
    const _Float16* __restrict__ A0, const _Float16* __restrict__ B0, void* __restrict__ C0,
    int K, int lda, int ldb, int ldc,
    int az_div, long sa_hi, long sa_lo, long sb,
    int cz_div, long sc_hi, long sc_lo)
{
    __shared__ _Float16 As[2][RB * 32 * 64];
    __shared__ _Float16 Bs[2][128 * 64];
    int bx, by, bz;
    if (XS) {
        int p = blockIdx.x;
        int xcd = p & 7, s = p >> 3;
        int c, within;
        if (s < 256) { c = xcd + 8 * (s >> 6); within = s & 63; }
        else         { c = 32 + (xcd >> 2); within = (xcd & 3) * 16 + (s - 256); }
        bz = c >> 1;
        by = (c & 1) * 8 + (within >> 3);
        bx = within & 7;
    } else { bx = blockIdx.x; by = blockIdx.y; bz = blockIdx.z; }
    int z = bz;
    const _Float16* A = A0 + (long)(z / az_div) * sa_hi + (long)(z % az_div) * sa_lo;
    const _Float16* B = B0 + (long)z * sb;
    long coff = (long)(z / cz_div) * sc_hi + (long)(z % cz_div) * sc_lo;
    int rowbase = by * (RB * 32), colbase = bx * 128;
    int t = threadIdx.x, wave = t >> 6, lane = t & 63;
    int l15 = lane & 15, lg = lane >> 4;
    int srow = t >> 3, scol = (t & 7) * 8;
    int wm = wave >> 1, wn = wave & 1;
    f32x4 acc[RB][4] = {};
    const int nt = K >> 6;

    #pragma unroll
    for (int ii = 0; ii < RB; ii++) {
        int r = srow + ii * 32;
        async16(&As[0][r * 64 + scol], A + (long)(rowbase + r) * lda + scol);
    }
    #pragma unroll
    for (int ii = 0; ii < 4; ii++) {
        int r = srow + ii * 32;
        async16(&Bs[0][r * 64 + scol], B + (long)(colbase + r) * ldb + scol);
    }

    for (int ts = 0; ts < nt; ts++) {
        __syncthreads();
        if (ts + 1 < nt) {
            int k1 = (ts + 1) << 6;
            int p1 = (ts + 1) & 1;
            #pragma unroll
            for (int ii = 0; ii < RB; ii++) {
                int r = srow + ii * 32;
                async16(&As[p1][r * 64 + scol], A + (long)(rowbase + r) * lda + k1 + scol);
            }
            #pragma unroll
            for (int ii = 0; ii < 4; ii++) {
                int r = srow + ii * 32;
                async16(&Bs[p1][r * 64 + scol], B + (long)(colbase + r) * ldb + k1 + scol);
            }
        }
        int pc = ts & 1;
        #pragma unroll
        for (int ks = 0; ks < 2; ks++) {
            f16x8 af[RB], bfr[4];
            #pragma unroll
            for (int m = 0; m < RB; m++)
                af[m] = *(const f16x8*)&As[pc][(wm * (RB * 16) + m * 16 + l15) * 64 + ks * 32 + lg * 8];
            #pragma unroll
            for (int n = 0; n < 4; n++)
                bfr[n] = *(const f16x8*)&Bs[pc][(wn * 64 + n * 16 + l15) * 64 + ks * 32 + lg * 8];
            #pragma unroll
            for (int m = 0; m < RB; m++)
                #pragma unroll
                for (int n = 0; n < 4; n++)
                    acc[m][n] = __builtin_amdgcn_mfma_f32_16x16x32_f16(af[m], bfr[n], acc[m][n], 0, 0, 0);
        }
    }
    #pragma unroll
    for (int m = 0; m < RB; m++) {
        int row = rowbase + wm * (RB * 16) + m * 16 + lg * 4;
        #pragma unroll
        for (int n = 0; n < 4; n++) {
            int col = colbase + wn * 64 + n * 16 + l15;
            #pragma unroll
            for (int r = 0; r < 4; r++) {
                long idx = coff + (long)(row + r) * ldc + col;
                if (OMODE == 1) ((float*)C0)[idx] = acc[m][n][r];
                else ((_Float16*)C0)[idx] = (_Float16)acc[m][n][r];
            }
        }
    }
}

// ---------------- fused attn v12: 4-wave blocks, 16KB chunks, depth-3 counted vmcnt ----------------
// 1024 blocks (XCD-swizzled), 256 threads = 4 waves; block = 16 t-rows x 1024 s
// of one (b,h). Chunk = 64 K-rows (16 KB); 4 LDS bufs (64 KB) -> 2 blocks/CU
// (v11's depth WITHOUT v11's residency loss). 128 steps m=i*16+c.
// Step: {s_waitcnt vmcnt(8) lgkmcnt(0) -> s_barrier -> issue stage((m+3)&127,
//        buf (c+3)&3) -> 4 ds_read_b128 + 4 MFMA + 16 exp}.
// vmcnt(8): 2 chunks (8 ops) in flight; FIFO retire => stage(m) landed.
// lgkmcnt(0) before barrier: step m-1's reads of buf (c+3)&3 done => write safe.
// Reduction barriers lgkm-only (vmem pipeline survives head boundaries).
__global__ __launch_bounds__(256, 2) void attn_fused(
    const _Float16* __restrict__ Qbuf, const _Float16* __restrict__ Kbuf,
    float* __restrict__ attn_out, _Float16* __restrict__ Pbar)
{
    __shared__ _Float16 Kc[4][64 * 128];  // 4 x 16 KB
    __shared__ float red[4][16];
    int id = blockIdx.x;
    int orig = (id & 7) * 128 + (id >> 3);   // XCD k owns bh {2k,2k+1}
    int t0 = (orig & 63) * 16;
    int bh = orig >> 6, h = bh & 7, b = bh >> 3;
    int tid = threadIdx.x, wave = tid >> 6, lane = tid & 63;
    int l15 = lane & 15, lg = lane >> 4;
    int sw = wave;                       // 16-col subtile within the 64-row chunk
    int brow = sw * 16 + l15;            // 0..63
    const float scale = 0.088388347648318447f;  // 1/sqrt(128)
    float acc[16][4] = {};

    // staging: per thread rows {tid>>4, +16, +32, +48}, bytes (tid&15)*16
    int srow0 = tid >> 4;                 // 0..15
    int scolB = (tid & 15) << 4;
    int gcolB = scolB ^ ((srow0 & 7) << 4);   // (srow0+16j)&7 == srow0&7
    int ldsoff = tid * 16;                    // + j*4096 per op (linear dest)
    const char* pkb = (const char*)(Kbuf + (long)b * 1048576 + h * 128)
                      + (long)srow0 * 2048 + gcolB;
    const char* pq = (const char*)(Qbuf + ((long)(b * 1024 + t0 + l15)) * 1024 + h * 128)
                     + lg * 16;
    int swz = (brow & 7) << 4;
    int rdoff[4];
    #pragma unroll
    for (int kk = 0; kk < 4; kk++)
        rdoff[kk] = brow * 256 + ((kk * 64 + lg * 16) ^ swz);

    // prologue: chunks 0,1,2 of head 0 -> bufs 0,1,2
    #pragma unroll
    for (int mp = 0; mp < 3; mp++) {
        char* lb = (char*)Kc[mp] + ldsoff;
        const char* ps = pkb + (long)mp * 131072;
        #pragma unroll
        for (int j = 0; j < 4; j++)
            async16(lb + j * 4096, ps + (long)j * 32768);
    }

    #pragma unroll 1
    for (int i = 0; i < 8; i++) {
        f16x8 aq[4];
        #pragma unroll
        for (int kk = 0; kk < 4; kk++)
            aq[kk] = *(const f16x8*)(pq + kk * 64);
        pq += 4194304;   // next head (+2M f16)
        float s[16][4];
        float rs[4] = {0.f, 0.f, 0.f, 0.f};
        #pragma unroll
        for (int c = 0; c < 16; c++) {
            int m = i * 16 + c;
            asm volatile("s_waitcnt vmcnt(8) lgkmcnt(0)" ::: "memory");
            __builtin_amdgcn_s_barrier();
            {
                int n = (m + 3) & 127;   // wrap keeps FIFO uniform at tail
                char* lb = (char*)Kc[(c + 3) & 3] + ldsoff;
                const char* ps = pkb + (long)(n >> 4) * 4194304 + (long)(n & 15) * 131072;
                #pragma unroll
                for (int j = 0; j < 4; j++)
                    async16(lb + j * 4096, ps + (long)j * 32768);
            }
            const char* kc = (const char*)Kc[c & 3];
            f32x4 sv = {0.f, 0.f, 0.f, 0.f};
            #pragma unroll
            for (int kk = 0; kk < 4; kk++) {
                f16x8 bk = *(const f16x8*)(kc + rdoff[kk]);
                sv = __builtin_amdgcn_mfma_f32_16x16x32_f16(aq[kk], bk, sv, 0, 0, 0);
            }
            #pragma unroll
            for (int r = 0; r < 4; r++) {
                float e = __expf(sv[r] * scale);
                s[c][r] = e;
                rs[r] += e;
            }
        }
        // row-sum reduce: across l15 lanes, then across the 4 waves.
        #pragma unroll
        for (int off = 1; off < 16; off <<= 1)
            #pragma unroll
            for (int r = 0; r < 4; r++) rs[r] += __shfl_xor(rs[r], off, 64);
        if (l15 == 0) {
            #pragma unroll
            for (int r = 0; r < 4; r++) red[wave][lg * 4 + r] = rs[r];
        }
        asm volatile("s_waitcnt lgkmcnt(0)" ::: "memory");
        __builtin_amdgcn_s_barrier();
        #pragma unroll
        for (int r = 0; r < 4; r++) {
            int row = lg * 4 + r;
            float tot = red[0][row] + red[1][row] + red[2][row] + red[3][row];
            float rinv = 0.125f / tot;
            #pragma unroll
            for (int c = 0; c < 16; c++) acc[c][r] += s[c][r] * rinv;
        }
        asm volatile("s_waitcnt lgkmcnt(0)" ::: "memory");
        __builtin_amdgcn_s_barrier();
    }

    long rbase = ((long)(bh * 1024 + t0)) * 1024;
    #pragma unroll
    for (int c = 0; c < 16; c++) {
        int scol = c * 64 + sw * 16 + l15;
        #pragma unroll
        for (int r = 0; r < 4; r++) {
            long idx = rbase + (long)(lg * 4 + r) * 1024 + scol;
            attn_out[idx] = acc[c][r];
            Pbar[idx] = (_Float16)acc[c][r];
        }
    }
}

extern "C" void kernel_launch(void* const* d_in, const int* in_sizes, int n_in,
                              void* d_out, int out_size, void* d_ws, size_t ws_size,
                              hipStream_t stream) {
    const long M1 = 1048576;
    _Float16* ws = (_Float16*)d_ws;
    _Float16* q16  = ws;             // 2M elts (query; key at +2M, value at +4M)
    _Float16* wq16 = ws + 6 * M1;    // 8M (Wk at +8M, Wv at +16M)
    _Float16* wo16 = ws + 23 * M1;   // 1M
    _Float16* Qbuf = ws + 24 * M1;   // 16M row-major Q (Kbuf at +16M, Vbuf at +32M)
    _Float16* Vbuf = ws + 56 * M1;   // 2M  (== Qbuf + 32M)
    _Float16* Vt   = ws + 58 * M1;   // 2M
    _Float16* Pb   = ws + 60 * M1;   // 16M
    _Float16* Hbar = ws + 76 * M1;   // 2M
    float* out = (float*)d_out;
    float* attn_out = out + 2 * M1;

    // all 7 casts in one dispatch
    cast_all<<<2048, 256, 0, stream>>>(
        (const float*)d_in[0], (const float*)d_in[1], (const float*)d_in[2],
        (const float*)d_in[3], (const float*)d_in[4], (const float*)d_in[5],
        (const float*)d_in[6], ws);

    // Projections, one dispatch (XCD-chunk swizzled flat grid):
    // z=0..7 Q_i = query @ Wq[i]^T; z=8..15 K_i; z=16 V = value @ Wv^T.
    gemm_bt<4, 1, 0><<<2176, 256, 0, stream>>>(
        q16, wq16, Qbuf, 1024, 1024, 1024, 1024,
        /*az*/ 8, 2 * M1, 0, /*sb*/ M1,
        /*cz*/ 16, 32 * M1, 2 * M1);
    // V transpose -> Vt[b][e][s]
    transpose_v<<<dim3(16, 16, 2), 256, 0, stream>>>(Vbuf, Vt);
    // fused scores+softmax+mean_i -> attention (f32) + Pbar (f16)
    attn_fused<<<1024, 256, 0, stream>>>(Qbuf, Qbuf + 16 * M1, attn_out, Pb);
    // PV: head[b][t][h*128+n] = sum_s Pbar[(b,h)][t][s] * Vt[b][h*128+n][s]
    gemm_bt<2, 0, 0><<<dim3(1, 16, 16), 256, 0, stream>>>(
        Pb, Vt, Hbar, 1024, 1024, 1024, 1024,
        /*az*/ 16, 0, M1, /*sb*/ M1 / 8,
        /*cz*/ 8, M1, 128);
    // out = head_mean @ Wo^T  (f32 out)
    gemm_bt<2, 0, 1><<<dim3(8, 32, 1), 256, 0, stream>>>(
        Hbar, wo16, out, 1024, 1024, 1024, 1024,
        1, 0, 0, 0, 1, 0, 0);
}

// Round 14
// 266.116 us; speedup vs baseline: 1.3327x; 1.1433x over previous
//
#include <hip/hip_runtime.h>
#include <hip/hip_bf16.h>

typedef _Float16 f16x8 __attribute__((ext_vector_type(8)));
typedef _Float16 f16x4 __attribute__((ext_vector_type(4)));
typedef float f32x4 __attribute__((ext_vector_type(4)));

typedef __attribute__((address_space(1))) void GV;
typedef __attribute__((address_space(3))) void LV;

__device__ inline void async16(void* lds, const void* g) {
    __builtin_amdgcn_global_load_lds((GV*)g, (LV*)lds, 16, 0, 0);
}

// ---------------- fused cast f32 -> f16 for all 7 inputs ----------------
__global__ __launch_bounds__(256) void cast_all(
    const float* __restrict__ q, const float* __restrict__ k, const float* __restrict__ v,
    const float* __restrict__ wq, const float* __restrict__ wk,
    const float* __restrict__ wv, const float* __restrict__ wo, _Float16* __restrict__ ws)
{
    const long M1 = 1048576;
    const long tot = 6291456;  // total float4s
    for (long idx = (long)blockIdx.x * 256 + threadIdx.x; idx < tot;
         idx += (long)gridDim.x * 256) {
        const float* src; long local; long doff;
        if (idx < 1572864) {                    // q,k,v: 512K f4 each
            int seg = (int)(idx >> 19);
            src = seg == 0 ? q : (seg == 1 ? k : v);
            local = idx & 524287; doff = (long)seg * 2 * M1;
        } else if (idx < 5767168) {             // wq, wk: 2M f4 each
            int seg = (int)((idx - 1572864) >> 21);
            src = seg == 0 ? wq : wk;
            local = (idx - 1572864) & 2097151; doff = (6 + 8 * (long)seg) * M1;
        } else {                                 // wv, wo: 256K f4 each
            int seg = (int)((idx - 5767168) >> 18);
            src = seg == 0 ? wv : wo;
            local = (idx - 5767168) & 262143; doff = (22 + (long)seg) * M1;
        }
        float4 val = ((const float4*)src)[local];
        f16x4 o;
        o[0] = (_Float16)val.x; o[1] = (_Float16)val.y;
        o[2] = (_Float16)val.z; o[3] = (_Float16)val.w;
        *(f16x4*)&ws[doff + 4 * local] = o;
    }
}

// ---------------- V transpose: in [b][s][e] -> out [b][e][s] ----------------
__global__ __launch_bounds__(256) void transpose_v(const _Float16* __restrict__ in,
                                                   _Float16* __restrict__ out) {
    __shared__ _Float16 tile[64][66];
    int b = blockIdx.z;
    long base = (long)b * 1048576;
    int s0 = blockIdx.x * 64, e0 = blockIdx.y * 64;
    int tc = threadIdx.x & 63, tr = threadIdx.x >> 6;
    #pragma unroll
    for (int rr = 0; rr < 64; rr += 4)
        tile[tr + rr][tc] = in[base + (long)(s0 + tr + rr) * 1024 + e0 + tc];
    __syncthreads();
    #pragma unroll
    for (int rr = 0; rr < 64; rr += 4)
        out[base + (long)(e0 + tr + rr) * 1024 + s0 + tc] = tile[tc][tr + rr];
}

// ---------------- batched GEMM v3: counted-vmcnt depth-3 pipeline (attn-v12 skeleton) ----------------
// RB = row-fragments per wave (tile M = RB*32). XS: flat-grid XCD-chunk swizzle.
// OMODE: 0 = f16 row-major, 1 = f32 row-major.
// BK=32; chunk = A (RB*2KB) + B (8KB) staged fragment-blocked; 4 bufs ->
// 64 KB (RB=4) -> 2 blocks/CU with depth-3.
// Fragment-blocked LDS: each 16-row x 64-B fragment contiguous 1KB, slot
// (l15*4+lg) -> wave's ds_read_b128 of a fragment = contiguous 1KB, no bank
// conflicts. Global source permuted per-lane (legal for global_load_lds).
// Step: {vmcnt(2*ops) lgkmcnt(0) -> s_barrier -> stage((ts+3)&(nt-1), buf
// (ts+3)&3) -> reads+MFMA}. Wrap staging keeps FIFO uniform (v12-proven).
template<int RB, int XS, int OMODE>
__global__ __launch_bounds__(256, 2) void gemm_bt(
    const _Float16* __restrict__ A0, const _Float16* __restrict__ B0, void* __restrict__ C0,
    int K, int lda, int ldb, int ldc,
    int az_div, long sa_hi, long sa_lo, long sb,
    int cz_div, long sc_hi, long sc_lo)
{
    constexpr int ABYTES = RB * 2048;       // A bytes per chunk
    constexpr int BUFB = ABYTES + 8192;     // + B bytes
    __shared__ char Sb[4][BUFB];
    int bx, by, bz;
    if (XS) {
        int p = blockIdx.x;
        int xcd = p & 7, s = p >> 3;
        int c, within;
        if (s < 256) { c = xcd + 8 * (s >> 6); within = s & 63; }
        else         { c = 32 + (xcd >> 2); within = (xcd & 3) * 16 + (s - 256); }
        bz = c >> 1;
        by = (c & 1) * 8 + (within >> 3);
        bx = within & 7;
    } else { bx = blockIdx.x; by = blockIdx.y; bz = blockIdx.z; }
    int z = bz;
    const _Float16* A = A0 + (long)(z / az_div) * sa_hi + (long)(z % az_div) * sa_lo;
    const _Float16* B = B0 + (long)z * sb;
    long coff = (long)(z / cz_div) * sc_hi + (long)(z % cz_div) * sc_lo;
    int rowbase = by * (RB * 32), colbase = bx * 128;
    int t = threadIdx.x, wave = t >> 6, lane = t & 63;
    int l15 = lane & 15, lg = lane >> 4;
    int wm = wave >> 1, wn = wave & 1;
    f32x4 acc[RB][4] = {};
    const int nt = K >> 5;                  // 32-wide k-steps (power of 2)

    // staging geometry: slot s = t + 256j; frag = (t>>6)+4j, row-in-frag =
    // (t>>2)&15, byte-col = (t&3)*16. LDS dest = buf + [A: s*16 | B: ABYTES+s*16].
    int fA0 = t >> 6;
    int rrS = (t >> 2) & 15;
    int cbS = (t & 3) * 16;
    const char* pA = (const char*)(A + (long)(rowbase + fA0 * 16 + rrS) * lda) + cbS;
    const char* pB = (const char*)(B + (long)(colbase + fA0 * 16 + rrS) * ldb) + cbS;
    long ldaB = (long)lda * 128;            // 64 rows in bytes
    long ldbB = (long)ldb * 128;

    auto STAGE = [&](int buf, int kstep) {
        long kb = (long)kstep * 64;         // 32 f16 = 64 bytes
        char* lb = Sb[buf] + t * 16;
        #pragma unroll
        for (int j = 0; j < RB / 2; j++)
            async16(lb + j * 4096, pA + j * ldaB + kb);
        #pragma unroll
        for (int j = 0; j < 2; j++)
            async16(lb + ABYTES + j * 4096, pB + j * ldbB + kb);
    };

    int lslot = (l15 * 4 + lg) * 16;        // byte offset within a fragment

    // prologue: chunks 0,1,2 -> bufs 0,1,2
    STAGE(0, 0); STAGE(1, 1); STAGE(2, 2);

    for (int ts = 0; ts < nt; ts++) {
        if constexpr (RB == 4)
            asm volatile("s_waitcnt vmcnt(8) lgkmcnt(0)" ::: "memory");
        else
            asm volatile("s_waitcnt vmcnt(6) lgkmcnt(0)" ::: "memory");
        __builtin_amdgcn_s_barrier();
        STAGE((ts + 3) & 3, (ts + 3) & (nt - 1));   // wrap keeps FIFO uniform
        const char* sbuf = Sb[ts & 3];
        f16x8 af[RB], bfr[4];
        #pragma unroll
        for (int m = 0; m < RB; m++)
            af[m] = *(const f16x8*)(sbuf + (wm * RB + m) * 1024 + lslot);
        #pragma unroll
        for (int n = 0; n < 4; n++)
            bfr[n] = *(const f16x8*)(sbuf + ABYTES + (wn * 4 + n) * 1024 + lslot);
        #pragma unroll
        for (int m = 0; m < RB; m++)
            #pragma unroll
            for (int n = 0; n < 4; n++)
                acc[m][n] = __builtin_amdgcn_mfma_f32_16x16x32_f16(af[m], bfr[n], acc[m][n], 0, 0, 0);
    }
    #pragma unroll
    for (int m = 0; m < RB; m++) {
        int row = rowbase + wm * (RB * 16) + m * 16 + lg * 4;
        #pragma unroll
        for (int n = 0; n < 4; n++) {
            int col = colbase + wn * 64 + n * 16 + l15;
            #pragma unroll
            for (int r = 0; r < 4; r++) {
                long idx = coff + (long)(row + r) * ldc + col;
                if (OMODE == 1) ((float*)C0)[idx] = acc[m][n][r];
                else ((_Float16*)C0)[idx] = (_Float16)acc[m][n][r];
            }
        }
    }
}

// ---------------- fused attn v12: 4-wave blocks, 16KB chunks, depth-3 counted vmcnt ----------------
// (unchanged from R12 — 139 us champion)
__global__ __launch_bounds__(256, 2) void attn_fused(
    const _Float16* __restrict__ Qbuf, const _Float16* __restrict__ Kbuf,
    float* __restrict__ attn_out, _Float16* __restrict__ Pbar)
{
    __shared__ _Float16 Kc[4][64 * 128];  // 4 x 16 KB
    __shared__ float red[4][16];
    int id = blockIdx.x;
    int orig = (id & 7) * 128 + (id >> 3);   // XCD k owns bh {2k,2k+1}
    int t0 = (orig & 63) * 16;
    int bh = orig >> 6, h = bh & 7, b = bh >> 3;
    int tid = threadIdx.x, wave = tid >> 6, lane = tid & 63;
    int l15 = lane & 15, lg = lane >> 4;
    int sw = wave;
    int brow = sw * 16 + l15;
    const float scale = 0.088388347648318447f;  // 1/sqrt(128)
    float acc[16][4] = {};

    int srow0 = tid >> 4;
    int scolB = (tid & 15) << 4;
    int gcolB = scolB ^ ((srow0 & 7) << 4);
    int ldsoff = tid * 16;
    const char* pkb = (const char*)(Kbuf + (long)b * 1048576 + h * 128)
                      + (long)srow0 * 2048 + gcolB;
    const char* pq = (const char*)(Qbuf + ((long)(b * 1024 + t0 + l15)) * 1024 + h * 128)
                     + lg * 16;
    int swz = (brow & 7) << 4;
    int rdoff[4];
    #pragma unroll
    for (int kk = 0; kk < 4; kk++)
        rdoff[kk] = brow * 256 + ((kk * 64 + lg * 16) ^ swz);

    #pragma unroll
    for (int mp = 0; mp < 3; mp++) {
        char* lb = (char*)Kc[mp] + ldsoff;
        const char* ps = pkb + (long)mp * 131072;
        #pragma unroll
        for (int j = 0; j < 4; j++)
            async16(lb + j * 4096, ps + (long)j * 32768);
    }

    #pragma unroll 1
    for (int i = 0; i < 8; i++) {
        f16x8 aq[4];
        #pragma unroll
        for (int kk = 0; kk < 4; kk++)
            aq[kk] = *(const f16x8*)(pq + kk * 64);
        pq += 4194304;
        float s[16][4];
        float rs[4] = {0.f, 0.f, 0.f, 0.f};
        #pragma unroll
        for (int c = 0; c < 16; c++) {
            int m = i * 16 + c;
            asm volatile("s_waitcnt vmcnt(8) lgkmcnt(0)" ::: "memory");
            __builtin_amdgcn_s_barrier();
            {
                int n = (m + 3) & 127;
                char* lb = (char*)Kc[(c + 3) & 3] + ldsoff;
                const char* ps = pkb + (long)(n >> 4) * 4194304 + (long)(n & 15) * 131072;
                #pragma unroll
                for (int j = 0; j < 4; j++)
                    async16(lb + j * 4096, ps + (long)j * 32768);
            }
            const char* kc = (const char*)Kc[c & 3];
            f32x4 sv = {0.f, 0.f, 0.f, 0.f};
            #pragma unroll
            for (int kk = 0; kk < 4; kk++) {
                f16x8 bk = *(const f16x8*)(kc + rdoff[kk]);
                sv = __builtin_amdgcn_mfma_f32_16x16x32_f16(aq[kk], bk, sv, 0, 0, 0);
            }
            #pragma unroll
            for (int r = 0; r < 4; r++) {
                float e = __expf(sv[r] * scale);
                s[c][r] = e;
                rs[r] += e;
            }
        }
        #pragma unroll
        for (int off = 1; off < 16; off <<= 1)
            #pragma unroll
            for (int r = 0; r < 4; r++) rs[r] += __shfl_xor(rs[r], off, 64);
        if (l15 == 0) {
            #pragma unroll
            for (int r = 0; r < 4; r++) red[wave][lg * 4 + r] = rs[r];
        }
        asm volatile("s_waitcnt lgkmcnt(0)" ::: "memory");
        __builtin_amdgcn_s_barrier();
        #pragma unroll
        for (int r = 0; r < 4; r++) {
            int row = lg * 4 + r;
            float tot = red[0][row] + red[1][row] + red[2][row] + red[3][row];
            float rinv = 0.125f / tot;
            #pragma unroll
            for (int c = 0; c < 16; c++) acc[c][r] += s[c][r] * rinv;
        }
        asm volatile("s_waitcnt lgkmcnt(0)" ::: "memory");
        __builtin_amdgcn_s_barrier();
    }

    long rbase = ((long)(bh * 1024 + t0)) * 1024;
    #pragma unroll
    for (int c = 0; c < 16; c++) {
        int scol = c * 64 + sw * 16 + l15;
        #pragma unroll
        for (int r = 0; r < 4; r++) {
            long idx = rbase + (long)(lg * 4 + r) * 1024 + scol;
            attn_out[idx] = acc[c][r];
            Pbar[idx] = (_Float16)acc[c][r];
        }
    }
}

extern "C" void kernel_launch(void* const* d_in, const int* in_sizes, int n_in,
                              void* d_out, int out_size, void* d_ws, size_t ws_size,
                              hipStream_t stream) {
    const long M1 = 1048576;
    _Float16* ws = (_Float16*)d_ws;
    _Float16* q16  = ws;             // 2M elts (query; key at +2M, value at +4M)
    _Float16* wq16 = ws + 6 * M1;    // 8M (Wk at +8M, Wv at +16M)
    _Float16* wo16 = ws + 23 * M1;   // 1M
    _Float16* Qbuf = ws + 24 * M1;   // 16M row-major Q (Kbuf at +16M, Vbuf at +32M)
    _Float16* Vbuf = ws + 56 * M1;   // 2M  (== Qbuf + 32M)
    _Float16* Vt   = ws + 58 * M1;   // 2M
    _Float16* Pb   = ws + 60 * M1;   // 16M
    _Float16* Hbar = ws + 76 * M1;   // 2M
    float* out = (float*)d_out;
    float* attn_out = out + 2 * M1;

    // all 7 casts in one dispatch
    cast_all<<<2048, 256, 0, stream>>>(
        (const float*)d_in[0], (const float*)d_in[1], (const float*)d_in[2],
        (const float*)d_in[3], (const float*)d_in[4], (const float*)d_in[5],
        (const float*)d_in[6], ws);

    // Projections, one dispatch (XCD-chunk swizzled flat grid):
    // z=0..7 Q_i = query @ Wq[i]^T; z=8..15 K_i; z=16 V = value @ Wv^T.
    gemm_bt<4, 1, 0><<<2176, 256, 0, stream>>>(
        q16, wq16, Qbuf, 1024, 1024, 1024, 1024,
        /*az*/ 8, 2 * M1, 0, /*sb*/ M1,
        /*cz*/ 16, 32 * M1, 2 * M1);
    // V transpose -> Vt[b][e][s]
    transpose_v<<<dim3(16, 16, 2), 256, 0, stream>>>(Vbuf, Vt);
    // fused scores+softmax+mean_i -> attention (f32) + Pbar (f16)
    attn_fused<<<1024, 256, 0, stream>>>(Qbuf, Qbuf + 16 * M1, attn_out, Pb);
    // PV: head[b][t][h*128+n] = sum_s Pbar[(b,h)][t][s] * Vt[b][h*128+n][s]
    gemm_bt<2, 0, 0><<<dim3(1, 16, 16), 256, 0, stream>>>(
        Pb, Vt, Hbar, 1024, 1024, 1024, 1024,
        /*az*/ 16, 0, M1, /*sb*/ M1 / 8,
        /*cz*/ 8, M1, 128);
    // out = head_mean @ Wo^T  (f32 out)
    gemm_bt<2, 0, 1><<<dim3(8, 32, 1), 256, 0, stream>>>(
        Hbar, wo16, out, 1024, 1024, 1024, 1024,
        1, 0, 0, 0, 1, 0, 0);
}